// Round 1
// 427.068 us; speedup vs baseline: 1.0473x; 1.0473x over previous
//
#include <hip/hip_runtime.h>

constexpr int NTOK = 2048;
constexpr int CH   = 128;
constexpr int C4   = 32;
constexpr int NB   = 16;

typedef __attribute__((ext_vector_type(8))) __bf16 bf16x8;
typedef __attribute__((ext_vector_type(4))) float  f32x4;

__device__ __forceinline__ unsigned short f2bf(float f) {
  union { float f; unsigned u; } v; v.f = f;
  unsigned r = v.u + 0x7fffu + ((v.u >> 16) & 1u);
  return (unsigned short)(r >> 16);
}
__device__ __forceinline__ float bf2f(unsigned short h) {
  union { unsigned u; float f; } v; v.u = ((unsigned)h) << 16;
  return v.f;
}

// rowsumH[b][c] = sum_n x_h[b][c][n]  (fp64) — one wave per channel, no LDS/sync
__global__ __launch_bounds__(256) void rs_kernel(const float* __restrict__ x_h,
                                                 double* __restrict__ rowsumH) {
  const int lane = threadIdx.x & 63;
  const int c = blockIdx.x * 4 + (threadIdx.x >> 6);
  const int b = blockIdx.y;
  const float* rp = x_h + (size_t)(b * CH + c) * NTOK;
  double s = 0.0;
#pragma unroll
  for (int i = 0; i < 8; ++i) {
    float4 v = *(const float4*)(rp + (lane + 64 * i) * 4);
    s += (double)v.x + (double)v.y + (double)v.z + (double)v.w;
  }
  for (int off = 1; off <= 32; off <<= 1) s += __shfl_xor(s, off);
  if (lane == 0) rowsumH[b * CH + c] = s;
}

// q/k projection (fp32 + bf16 hi/lo, [B][N][32] k-contiguous layout).
// which==1 blocks additionally compute P (fp64, per-block redundant) and
// inv[m] = 1/(1e-9 + P . x_o[:,m]) for their 64-token slab from LDS-resident Xt.
__global__ __launch_bounds__(256) void prep_qk(const float* __restrict__ x_h,
                                               const float* __restrict__ x_o,
                                               const float* __restrict__ w_qk,
                                               const double* __restrict__ rowsumH,
                                               float* __restrict__ xhq_f32,
                                               float* __restrict__ xokT_f32,
                                               unsigned short* __restrict__ xhq_hi,
                                               unsigned short* __restrict__ xokT_hi,
                                               unsigned short* __restrict__ xhq_lo,
                                               unsigned short* __restrict__ xokT_lo,
                                               float* __restrict__ inv) {
  const int t = threadIdx.x;
  const int n0 = blockIdx.x * 64;
  const int b = blockIdx.y;
  const int which = blockIdx.z;
  const float* src = which ? x_o : x_h;
  float* dstf = which ? xokT_f32 : xhq_f32;
  unsigned short* dsth = which ? xokT_hi : xhq_hi;
  unsigned short* dstl = which ? xokT_lo : xhq_lo;

  __shared__ float Xt[CH][64];
  __shared__ float Wl[C4][132];
  __shared__ double Sl[C4];
  __shared__ double Pl[CH];

  for (int i = 0; i < 8; ++i) {
    int flat = t + 256 * i;            // float4 units, 2048 total
    int c = flat >> 4, f4 = flat & 15;
    float4 v = *(const float4*)(src + (size_t)(b * CH + c) * NTOK + n0 + f4 * 4);
    *(float4*)&Xt[c][f4 * 4] = v;
  }
  for (int i = 0; i < 4; ++i) {
    int flat = t + 256 * i;            // float4 units, 1024 total
    int d = flat >> 5, f4 = flat & 31;
    float4 v = *(const float4*)(w_qk + d * CH + f4 * 4);
    *(float4*)&Wl[d][f4 * 4] = v;
  }
  __syncthreads();

  const int nb = (t & 15) * 4;
  const int d0 = (t >> 4) * 2;
  float acc[4][2] = {};
#pragma unroll 4
  for (int c = 0; c < CH; ++c) {
    float4 x4 = *(const float4*)&Xt[c][nb];
    float w0 = Wl[d0][c], w1 = Wl[d0 + 1][c];
    acc[0][0] += x4.x * w0; acc[0][1] += x4.x * w1;
    acc[1][0] += x4.y * w0; acc[1][1] += x4.y * w1;
    acc[2][0] += x4.z * w0; acc[2][1] += x4.z * w1;
    acc[3][0] += x4.w * w0; acc[3][1] += x4.w * w1;
  }

  const size_t robase = (size_t)(b * NTOK + n0 + nb);
#pragma unroll
  for (int i = 0; i < 4; ++i) {
    size_t base = (robase + i) * C4 + d0;
    *(float2*)(dstf + base) = make_float2(acc[i][0], acc[i][1]);
    unsigned short h0 = f2bf(acc[i][0]), h1 = f2bf(acc[i][1]);
    *(unsigned*)(dsth + base) = (unsigned)h0 | ((unsigned)h1 << 16);
    unsigned short l0 = f2bf(acc[i][0] - bf2f(h0));
    unsigned short l1 = f2bf(acc[i][1] - bf2f(h1));
    *(unsigned*)(dstl + base) = (unsigned)l0 | ((unsigned)l1 << 16);
  }

  if (which) {
    // Sl[d] = sum_c w_qk[d][c] * rowsumH[b][c]   (fp64)
    if (t < C4) {
      double s = 0.0;
      for (int c = 0; c < CH; ++c) s += (double)Wl[t][c] * rowsumH[b * CH + c];
      Sl[t] = s;
    }
    __syncthreads();
    // Pl[c] = sum_d Sl[d] * w_qk[d][c]           (fp64)
    if (t < CH) {
      double p = 0.0;
      for (int d = 0; d < C4; ++d) p += Sl[d] * (double)Wl[d][t];
      Pl[t] = p;
    }
    __syncthreads();
    // inv[m] = 1/(1e-9 + Pl . x_o[:,m]) for the 64 tokens resident in Xt
    if (t < 64) {
      double s = 0.0;
      for (int c = 0; c < CH; ++c) s += Pl[c] * (double)Xt[c][t];
      inv[b * NTOK + n0 + t] = (float)(1.0 / (1e-9 + s));
    }
  }
}

// U4[b][slab][d][c'] = sum_{m in slab} xo_k[d][m]*inv[m]*x_o[b][c'][m]  (no atomics)
__global__ __launch_bounds__(256) void u_kernel(const float* __restrict__ x_o,
                                                const float* __restrict__ xokT_f32,
                                                const float* __restrict__ inv,
                                                float* __restrict__ U4) {
  const int t = threadIdx.x;
  const int c0 = blockIdx.x * 8;
  const int slab = blockIdx.y;
  const int mbase0 = slab * 512;
  const int b = blockIdx.z;
  const int d = t & 31, cl = t >> 5;
  __shared__ float Xs[8][256];
  float acc = 0.f;
  for (int cc = 0; cc < 2; ++cc) {
    const int mb = mbase0 + cc * 256;
    __syncthreads();
    for (int i = 0; i < 2; ++i) {
      int flat = t + 256 * i;          // float4 units, 512 total
      int row = flat >> 6, f4 = flat & 63;
      float4 xv = *(const float4*)(x_o + (size_t)(b * CH + c0 + row) * NTOK + mb + f4 * 4);
      float4 iv = *(const float4*)(inv + b * NTOK + mb + f4 * 4);
      xv.x *= iv.x; xv.y *= iv.y; xv.z *= iv.z; xv.w *= iv.w;
      *(float4*)&Xs[row][f4 * 4] = xv;
    }
    __syncthreads();
    const float* ap = xokT_f32 + (size_t)(b * NTOK + mb) * C4 + d;
#pragma unroll 4
    for (int mm = 0; mm < 256; mm += 4) {
      float4 xq = *(const float4*)&Xs[cl][mm];
      float a0 = ap[(mm + 0) * C4];
      float a1 = ap[(mm + 1) * C4];
      float a2 = ap[(mm + 2) * C4];
      float a3 = ap[(mm + 3) * C4];
      acc += a0 * xq.x + a1 * xq.y + a2 * xq.z + a3 * xq.w;
    }
  }
  U4[(size_t)((b * 4 + slab) * C4 + d) * CH + c0 + cl] = acc;
}

// T[b][d][c] = sum_c' (sum_slab U4)*w_v[c][c'] + S2[b][d]*b_v[c]
// S2[b][d] = sum_m xo_k[d][m]*inv[m], computed inline from xokT_f32.
__global__ __launch_bounds__(256) void t_kernel(const float* __restrict__ U4,
                                                const float* __restrict__ w_v,
                                                const float* __restrict__ b_v,
                                                const float* __restrict__ xokT_f32,
                                                const float* __restrict__ inv,
                                                float* __restrict__ T) {
  const int t = threadIdx.x, b = blockIdx.x;
  __shared__ float Wl[CH * CH];
  __shared__ float S2s[8][C4];
  const int d = t & 31;
  const int g = t >> 5;
  {
    const float* kp = xokT_f32 + (size_t)b * NTOK * C4;
    const float* ip = inv + b * NTOK;
    float s = 0.f;
    for (int m = g * 256; m < g * 256 + 256; ++m) s += kp[(size_t)m * C4 + d] * ip[m];
    S2s[g][d] = s;
  }
  for (int i = 0; i < 16; ++i) {
    int flat = t + 256 * i;            // float4 units, 4096 total
    *(float4*)&Wl[flat * 4] = *(const float4*)(w_v + flat * 4);
  }
  __syncthreads();
  float s2 = 0.f;
#pragma unroll
  for (int gg = 0; gg < 8; ++gg) s2 += S2s[gg][d];
  const int cg = g * 16;
  float acc[16] = {};
  const float* up = U4 + (size_t)(b * 4 * C4 + d) * CH;  // slab stride = C4*CH floats
  for (int cp = 0; cp < CH; ++cp) {
    float u = up[cp] + up[C4 * CH + cp] + up[2 * C4 * CH + cp] + up[3 * C4 * CH + cp];
#pragma unroll
    for (int j = 0; j < 16; ++j) acc[j] += u * Wl[(cg + j) * CH + cp];
  }
#pragma unroll
  for (int j = 0; j < 16; ++j) acc[j] += s2 * b_v[cg + j];
  float* tp = T + (size_t)(b * C4 + d) * CH + cg;
#pragma unroll
  for (int j = 0; j < 16; j += 4)
    *(float4*)(tp + j) = make_float4(acc[j], acc[j + 1], acc[j + 2], acc[j + 3]);
}

// out0[b][c][n] = sum_d xh_q[b][n][d] * T[b][d][c]
__global__ __launch_bounds__(256) void xr_kernel(const float* __restrict__ xhq_f32,
                                                 const float* __restrict__ T,
                                                 float* __restrict__ out0) {
  const int t = threadIdx.x;
  const int n = blockIdx.x * 256 + t;
  const int b = blockIdx.y;
  __shared__ float Tl[CH][36];
  for (int i = 0; i < 16; ++i) {
    int flat = t + 256 * i;            // 4096 floats
    int d = flat >> 7, c = flat & 127;
    Tl[c][d] = T[(size_t)b * C4 * CH + flat];
  }
  __syncthreads();
  float xq[C4];
  const float* qp = xhq_f32 + (size_t)(b * NTOK + n) * C4;
#pragma unroll
  for (int i = 0; i < 8; ++i) {
    float4 v = *(const float4*)(qp + i * 4);
    xq[i * 4] = v.x; xq[i * 4 + 1] = v.y; xq[i * 4 + 2] = v.z; xq[i * 4 + 3] = v.w;
  }
  float* op = out0 + (size_t)b * CH * NTOK + n;
  for (int c = 0; c < CH; ++c) {
    float acc = 0.f;
#pragma unroll
    for (int dd = 0; dd < C4; dd += 4) {
      float4 tv = *(const float4*)&Tl[c][dd];
      acc += xq[dd] * tv.x + xq[dd + 1] * tv.y + xq[dd + 2] * tv.z + xq[dd + 3] * tv.w;
    }
    op[(size_t)c * NTOK] = acc;
  }
}

// attention[b][n][m] = (xh_q[n,:] . xo_k[:,m]) * inv[m], bf16 hi/lo split MFMA
__global__ __launch_bounds__(256) void attn_kernel(const unsigned short* __restrict__ xhq_hi,
                                                   const unsigned short* __restrict__ xhq_lo,
                                                   const unsigned short* __restrict__ xokT_hi,
                                                   const unsigned short* __restrict__ xokT_lo,
                                                   const float* __restrict__ inv,
                                                   float* __restrict__ out1) {
  const int t = threadIdx.x;
  const int wave = t >> 6, lane = t & 63;
  const int quad = lane >> 4, l16 = lane & 15;
  const int m0 = blockIdx.x * 64;
  const int n0 = blockIdx.y * 64;
  const int b = blockIdx.z;

  const int n = n0 + wave * 16 + l16;
  const size_t abase = (size_t)(b * NTOK + n) * C4 + quad * 8;
  bf16x8 ah = *(const bf16x8*)(const void*)(xhq_hi + abase);
  bf16x8 al = *(const bf16x8*)(const void*)(xhq_lo + abase);

  bf16x8 bh[4], bl[4];
  float invv[4];
#pragma unroll
  for (int tt = 0; tt < 4; ++tt) {
    int m = m0 + tt * 16 + l16;
    size_t bbase = (size_t)(b * NTOK + m) * C4 + quad * 8;
    bh[tt] = *(const bf16x8*)(const void*)(xokT_hi + bbase);
    bl[tt] = *(const bf16x8*)(const void*)(xokT_lo + bbase);
    invv[tt] = inv[b * NTOK + m];
  }

  const int nrow = n0 + wave * 16 + quad * 4;
#pragma unroll
  for (int tt = 0; tt < 4; ++tt) {
    f32x4 z = {0.f, 0.f, 0.f, 0.f};
    f32x4 acc = __builtin_amdgcn_mfma_f32_16x16x32_bf16(al, bh[tt], z, 0, 0, 0);
    acc = __builtin_amdgcn_mfma_f32_16x16x32_bf16(ah, bl[tt], acc, 0, 0, 0);
    acc = __builtin_amdgcn_mfma_f32_16x16x32_bf16(ah, bh[tt], acc, 0, 0, 0);
#pragma unroll
    for (int r = 0; r < 4; ++r) {
      float v = acc[r] * invv[tt];
      size_t off = ((size_t)(b * NTOK) + nrow + r) * NTOK + m0 + tt * 16 + l16;
      __builtin_nontemporal_store(v, out1 + off);
    }
  }
}

extern "C" void kernel_launch(void* const* d_in, const int* in_sizes, int n_in,
                              void* d_out, int out_size, void* d_ws, size_t ws_size,
                              hipStream_t stream) {
  (void)in_sizes; (void)n_in; (void)out_size; (void)ws_size;
  const float* x_h  = (const float*)d_in[0];
  const float* x_o  = (const float*)d_in[1];
  const float* w_qk = (const float*)d_in[2];
  const float* w_v  = (const float*)d_in[3];
  const float* b_v  = (const float*)d_in[4];
  float* out0 = (float*)d_out;
  float* out1 = out0 + (size_t)NB * CH * NTOK;   // 4,194,304 floats

  char* ws = (char*)d_ws;
  float* xhq_f32        = (float*)(ws + 0);
  float* xokT_f32       = (float*)(ws + 4194304);
  unsigned short* xhq_hi  = (unsigned short*)(ws + 8388608);
  unsigned short* xokT_hi = (unsigned short*)(ws + 10485760);
  unsigned short* xhq_lo  = (unsigned short*)(ws + 12582912);
  unsigned short* xokT_lo = (unsigned short*)(ws + 14680064);
  float* inv      = (float*)(ws + 16777216);   // 128 KB
  float* U4       = (float*)(ws + 16908288);   // 1 MB (4 slabs of partials)
  float* T        = (float*)(ws + 17956864);   // 256 KB
  double* rowsumH = (double*)(ws + 18219008);  // 16 KB

  rs_kernel <<<dim3(32, NB), 256, 0, stream>>>(x_h, rowsumH);
  prep_qk   <<<dim3(32, NB, 2), 256, 0, stream>>>(x_h, x_o, w_qk, rowsumH,
                                                  xhq_f32, xokT_f32,
                                                  xhq_hi, xokT_hi, xhq_lo, xokT_lo, inv);
  u_kernel  <<<dim3(16, 4, NB), 256, 0, stream>>>(x_o, xokT_f32, inv, U4);
  t_kernel  <<<NB, 256, 0, stream>>>(U4, w_v, b_v, xokT_f32, inv, T);
  xr_kernel <<<dim3(8, NB), 256, 0, stream>>>(xhq_f32, T, out0);
  attn_kernel<<<dim3(32, 32, NB), 256, 0, stream>>>(xhq_hi, xhq_lo, xokT_hi, xokT_lo,
                                                    inv, out1);
}

// Round 3
// 387.117 us; speedup vs baseline: 1.1553x; 1.1032x over previous
//
#include <hip/hip_runtime.h>

constexpr int NTOK = 2048;
constexpr int CH   = 128;
constexpr int C4   = 32;
constexpr int NB   = 16;

typedef __attribute__((ext_vector_type(8))) __bf16 bf16x8;
typedef __attribute__((ext_vector_type(4))) float  f32x4;

__device__ __forceinline__ unsigned short f2bf(float f) {
  union { float f; unsigned u; } v; v.f = f;
  unsigned r = v.u + 0x7fffu + ((v.u >> 16) & 1u);
  return (unsigned short)(r >> 16);
}
__device__ __forceinline__ float bf2f(unsigned short h) {
  union { unsigned u; float f; } v; v.u = ((unsigned)h) << 16;
  return v.f;
}

// rowsumH[b][c] = sum_n x_h[b][c][n]  (fp64) — one wave per channel, no LDS/sync
__global__ __launch_bounds__(256) void rs_kernel(const float* __restrict__ x_h,
                                                 double* __restrict__ rowsumH) {
  const int lane = threadIdx.x & 63;
  const int c = blockIdx.x * 4 + (threadIdx.x >> 6);
  const int b = blockIdx.y;
  const float* rp = x_h + (size_t)(b * CH + c) * NTOK;
  double s = 0.0;
#pragma unroll
  for (int i = 0; i < 8; ++i) {
    float4 v = *(const float4*)(rp + (lane + 64 * i) * 4);
    s += (double)v.x + (double)v.y + (double)v.z + (double)v.w;
  }
  for (int off = 1; off <= 32; off <<= 1) s += __shfl_xor(s, off);
  if (lane == 0) rowsumH[b * CH + c] = s;
}

// q/k projection (fp32 + bf16 hi/lo, [B][N][32] k-contiguous layout).
// which==1 blocks additionally compute P (fp64, per-block redundant) and
// inv[m] = 1/(1e-9 + P . x_o[:,m]) for their 64-token slab from LDS-resident Xt.
__global__ __launch_bounds__(256) void prep_qk(const float* __restrict__ x_h,
                                               const float* __restrict__ x_o,
                                               const float* __restrict__ w_qk,
                                               const double* __restrict__ rowsumH,
                                               float* __restrict__ xhq_f32,
                                               float* __restrict__ xokT_f32,
                                               unsigned short* __restrict__ xhq_hi,
                                               unsigned short* __restrict__ xokT_hi,
                                               unsigned short* __restrict__ xhq_lo,
                                               unsigned short* __restrict__ xokT_lo,
                                               float* __restrict__ inv) {
  const int t = threadIdx.x;
  const int n0 = blockIdx.x * 64;
  const int b = blockIdx.y;
  const int which = blockIdx.z;
  const float* src = which ? x_o : x_h;
  float* dstf = which ? xokT_f32 : xhq_f32;
  unsigned short* dsth = which ? xokT_hi : xhq_hi;
  unsigned short* dstl = which ? xokT_lo : xhq_lo;

  __shared__ float Xt[CH][64];
  __shared__ float Wl[C4][132];
  __shared__ double Sl[C4];
  __shared__ double Pl[CH];

  for (int i = 0; i < 8; ++i) {
    int flat = t + 256 * i;            // float4 units, 2048 total
    int c = flat >> 4, f4 = flat & 15;
    float4 v = *(const float4*)(src + (size_t)(b * CH + c) * NTOK + n0 + f4 * 4);
    *(float4*)&Xt[c][f4 * 4] = v;
  }
  for (int i = 0; i < 4; ++i) {
    int flat = t + 256 * i;            // float4 units, 1024 total
    int d = flat >> 5, f4 = flat & 31;
    float4 v = *(const float4*)(w_qk + d * CH + f4 * 4);
    *(float4*)&Wl[d][f4 * 4] = v;
  }
  __syncthreads();

  const int nb = (t & 15) * 4;
  const int d0 = (t >> 4) * 2;
  float acc[4][2] = {};
#pragma unroll 4
  for (int c = 0; c < CH; ++c) {
    float4 x4 = *(const float4*)&Xt[c][nb];
    float w0 = Wl[d0][c], w1 = Wl[d0 + 1][c];
    acc[0][0] += x4.x * w0; acc[0][1] += x4.x * w1;
    acc[1][0] += x4.y * w0; acc[1][1] += x4.y * w1;
    acc[2][0] += x4.z * w0; acc[2][1] += x4.z * w1;
    acc[3][0] += x4.w * w0; acc[3][1] += x4.w * w1;
  }

  const size_t robase = (size_t)(b * NTOK + n0 + nb);
#pragma unroll
  for (int i = 0; i < 4; ++i) {
    size_t base = (robase + i) * C4 + d0;
    *(float2*)(dstf + base) = make_float2(acc[i][0], acc[i][1]);
    unsigned short h0 = f2bf(acc[i][0]), h1 = f2bf(acc[i][1]);
    *(unsigned*)(dsth + base) = (unsigned)h0 | ((unsigned)h1 << 16);
    unsigned short l0 = f2bf(acc[i][0] - bf2f(h0));
    unsigned short l1 = f2bf(acc[i][1] - bf2f(h1));
    *(unsigned*)(dstl + base) = (unsigned)l0 | ((unsigned)l1 << 16);
  }

  if (which) {
    // Sl[d] = sum_c w_qk[d][c] * rowsumH[b][c]   (fp64)
    if (t < C4) {
      double s = 0.0;
      for (int c = 0; c < CH; ++c) s += (double)Wl[t][c] * rowsumH[b * CH + c];
      Sl[t] = s;
    }
    __syncthreads();
    // Pl[c] = sum_d Sl[d] * w_qk[d][c]           (fp64)
    if (t < CH) {
      double p = 0.0;
      for (int d = 0; d < C4; ++d) p += Sl[d] * (double)Wl[d][t];
      Pl[t] = p;
    }
    __syncthreads();
    // inv[m] = 1/(1e-9 + Pl . x_o[:,m]) for the 64 tokens resident in Xt
    if (t < 64) {
      double s = 0.0;
      for (int c = 0; c < CH; ++c) s += Pl[c] * (double)Xt[c][t];
      inv[b * NTOK + n0 + t] = (float)(1.0 / (1e-9 + s));
    }
  }
}

// U4[b][slab][d][c'] = sum_{m in slab} xo_k[d][m]*inv[m]*x_o[b][c'][m]  (no atomics)
__global__ __launch_bounds__(256) void u_kernel(const float* __restrict__ x_o,
                                                const float* __restrict__ xokT_f32,
                                                const float* __restrict__ inv,
                                                float* __restrict__ U4) {
  const int t = threadIdx.x;
  const int c0 = blockIdx.x * 8;
  const int slab = blockIdx.y;
  const int mbase0 = slab * 512;
  const int b = blockIdx.z;
  const int d = t & 31, cl = t >> 5;
  __shared__ float Xs[8][256];
  float acc = 0.f;
  for (int cc = 0; cc < 2; ++cc) {
    const int mb = mbase0 + cc * 256;
    __syncthreads();
    for (int i = 0; i < 2; ++i) {
      int flat = t + 256 * i;          // float4 units, 512 total
      int row = flat >> 6, f4 = flat & 63;
      float4 xv = *(const float4*)(x_o + (size_t)(b * CH + c0 + row) * NTOK + mb + f4 * 4);
      float4 iv = *(const float4*)(inv + b * NTOK + mb + f4 * 4);
      xv.x *= iv.x; xv.y *= iv.y; xv.z *= iv.z; xv.w *= iv.w;
      *(float4*)&Xs[row][f4 * 4] = xv;
    }
    __syncthreads();
    const float* ap = xokT_f32 + (size_t)(b * NTOK + mb) * C4 + d;
#pragma unroll 4
    for (int mm = 0; mm < 256; mm += 4) {
      float4 xq = *(const float4*)&Xs[cl][mm];
      float a0 = ap[(mm + 0) * C4];
      float a1 = ap[(mm + 1) * C4];
      float a2 = ap[(mm + 2) * C4];
      float a3 = ap[(mm + 3) * C4];
      acc += a0 * xq.x + a1 * xq.y + a2 * xq.z + a3 * xq.w;
    }
  }
  U4[(size_t)((b * 4 + slab) * C4 + d) * CH + c0 + cl] = acc;
}

// T[b][d][c] = sum_c' (sum_slab U4)*w_v[c][c'] + S2[b][d]*b_v[c]
// grid (8 cgroups, NB); each block: 32 d x 16 c. S2 computed redundantly per block
// (2 MB L2 reads total, ~0.3 us).
__global__ __launch_bounds__(256) void t_kernel(const float* __restrict__ U4,
                                                const float* __restrict__ w_v,
                                                const float* __restrict__ b_v,
                                                const float* __restrict__ xokT_f32,
                                                const float* __restrict__ inv,
                                                float* __restrict__ T) {
  const int t = threadIdx.x;
  const int cgrp = blockIdx.x;           // c block of 16
  const int b = blockIdx.y;
  const int d = t & 31;
  const int g = t >> 5;                  // 0..7
  __shared__ float Wl[16][CH];           // w_v rows cgrp*16 .. +16
  __shared__ float S2s[8][C4];
  {
    const float* kp = xokT_f32 + (size_t)b * NTOK * C4;
    const float* ip = inv + b * NTOK;
    float s = 0.f;
    for (int m = g * 256; m < g * 256 + 256; ++m) s += kp[(size_t)m * C4 + d] * ip[m];
    S2s[g][d] = s;
  }
  for (int i = 0; i < 2; ++i) {
    int flat = t + 256 * i;              // float4 units, 512 total (16*128/4)
    *(float4*)&Wl[0][flat * 4] = *(const float4*)(w_v + (size_t)cgrp * 16 * CH + flat * 4);
  }
  __syncthreads();
  float s2 = 0.f;
#pragma unroll
  for (int gg = 0; gg < 8; ++gg) s2 += S2s[gg][d];
  const int c0 = g * 2;                  // local c pair
  float acc0 = 0.f, acc1 = 0.f;
  const float* up = U4 + (size_t)(b * 4 * C4 + d) * CH;  // slab stride = C4*CH floats
  for (int cp = 0; cp < CH; ++cp) {
    float u = up[cp] + up[C4 * CH + cp] + up[2 * C4 * CH + cp] + up[3 * C4 * CH + cp];
    acc0 += u * Wl[c0][cp];
    acc1 += u * Wl[c0 + 1][cp];
  }
  const int cglob = cgrp * 16 + c0;
  acc0 += s2 * b_v[cglob];
  acc1 += s2 * b_v[cglob + 1];
  *(float2*)(T + (size_t)(b * C4 + d) * CH + cglob) = make_float2(acc0, acc1);
}

// out0[b][c][n] = sum_d xh_q[b][n][d] * T[b][d][c]
// 512 threads: 128 n x 4 c-quarters; grid (16, NB)
__global__ __launch_bounds__(512) void xr_kernel(const float* __restrict__ xhq_f32,
                                                 const float* __restrict__ T,
                                                 float* __restrict__ out0) {
  const int t = threadIdx.x;
  const int nl = t & 127;
  const int half = t >> 7;               // 0..3 -> c range half*32..+32
  const int n = blockIdx.x * 128 + nl;
  const int b = blockIdx.y;
  __shared__ float Tl[CH][36];
  for (int i = 0; i < 8; ++i) {
    int flat = t + 512 * i;              // 4096 floats
    int d = flat >> 7, c = flat & 127;
    Tl[c][d] = T[(size_t)b * C4 * CH + flat];
  }
  __syncthreads();
  float xq[C4];
  const float* qp = xhq_f32 + (size_t)(b * NTOK + n) * C4;
#pragma unroll
  for (int i = 0; i < 8; ++i) {
    float4 v = *(const float4*)(qp + i * 4);
    xq[i * 4] = v.x; xq[i * 4 + 1] = v.y; xq[i * 4 + 2] = v.z; xq[i * 4 + 3] = v.w;
  }
  float* op = out0 + (size_t)b * CH * NTOK + n;
  for (int c = half * 32; c < half * 32 + 32; ++c) {
    float acc = 0.f;
#pragma unroll
    for (int dd = 0; dd < C4; dd += 4) {
      float4 tv = *(const float4*)&Tl[c][dd];
      acc += xq[dd] * tv.x + xq[dd + 1] * tv.y + xq[dd + 2] * tv.z + xq[dd + 3] * tv.w;
    }
    op[(size_t)c * NTOK] = acc;
  }
}

// attention[b][n][m] = (xh_q[n,:] . xo_k[:,m]) * inv[m], bf16 hi/lo split MFMA.
// Output tile staged in LDS, then stored as full-line 16B nt stores (ext_vector f32x4:
// __builtin_nontemporal_store rejects HIP_vector_type float4).
__global__ __launch_bounds__(256) void attn_kernel(const unsigned short* __restrict__ xhq_hi,
                                                   const unsigned short* __restrict__ xhq_lo,
                                                   const unsigned short* __restrict__ xokT_hi,
                                                   const unsigned short* __restrict__ xokT_lo,
                                                   const float* __restrict__ inv,
                                                   float* __restrict__ out1) {
  const int t = threadIdx.x;
  const int wave = t >> 6, lane = t & 63;
  const int quad = lane >> 4, l16 = lane & 15;
  const int m0 = blockIdx.x * 64;
  const int n0 = blockIdx.y * 64;
  const int b = blockIdx.z;

  __shared__ float tile[64][68];         // pad 68: writes 2-way (free), reads at b128 floor

  const int n = n0 + wave * 16 + l16;
  const size_t abase = (size_t)(b * NTOK + n) * C4 + quad * 8;
  bf16x8 ah = *(const bf16x8*)(const void*)(xhq_hi + abase);
  bf16x8 al = *(const bf16x8*)(const void*)(xhq_lo + abase);

  bf16x8 bh[4], bl[4];
  float invv[4];
#pragma unroll
  for (int tt = 0; tt < 4; ++tt) {
    int m = m0 + tt * 16 + l16;
    size_t bbase = (size_t)(b * NTOK + m) * C4 + quad * 8;
    bh[tt] = *(const bf16x8*)(const void*)(xokT_hi + bbase);
    bl[tt] = *(const bf16x8*)(const void*)(xokT_lo + bbase);
    invv[tt] = inv[b * NTOK + m];
  }

  const int trow = wave * 16 + quad * 4;
#pragma unroll
  for (int tt = 0; tt < 4; ++tt) {
    f32x4 z = {0.f, 0.f, 0.f, 0.f};
    f32x4 acc = __builtin_amdgcn_mfma_f32_16x16x32_bf16(al, bh[tt], z, 0, 0, 0);
    acc = __builtin_amdgcn_mfma_f32_16x16x32_bf16(ah, bl[tt], acc, 0, 0, 0);
    acc = __builtin_amdgcn_mfma_f32_16x16x32_bf16(ah, bh[tt], acc, 0, 0, 0);
#pragma unroll
    for (int r = 0; r < 4; ++r)
      tile[trow + r][tt * 16 + l16] = acc[r] * invv[tt];
  }
  __syncthreads();

  // read back row-major: wave w covers rows 4w+g (+16s), 16 lanes x 16B = full row
  const int g = lane >> 4;
#pragma unroll
  for (int s = 0; s < 4; ++s) {
    const int row = wave * 4 + g + s * 16;
    f32x4 v = *(const f32x4*)&tile[row][l16 * 4];
    float* dst = out1 + ((size_t)(b * NTOK) + n0 + row) * NTOK + m0 + l16 * 4;
    __builtin_nontemporal_store(v, (f32x4*)dst);
  }
}

extern "C" void kernel_launch(void* const* d_in, const int* in_sizes, int n_in,
                              void* d_out, int out_size, void* d_ws, size_t ws_size,
                              hipStream_t stream) {
  (void)in_sizes; (void)n_in; (void)out_size; (void)ws_size;
  const float* x_h  = (const float*)d_in[0];
  const float* x_o  = (const float*)d_in[1];
  const float* w_qk = (const float*)d_in[2];
  const float* w_v  = (const float*)d_in[3];
  const float* b_v  = (const float*)d_in[4];
  float* out0 = (float*)d_out;
  float* out1 = out0 + (size_t)NB * CH * NTOK;   // 4,194,304 floats

  char* ws = (char*)d_ws;
  float* xhq_f32        = (float*)(ws + 0);
  float* xokT_f32       = (float*)(ws + 4194304);
  unsigned short* xhq_hi  = (unsigned short*)(ws + 8388608);
  unsigned short* xokT_hi = (unsigned short*)(ws + 10485760);
  unsigned short* xhq_lo  = (unsigned short*)(ws + 12582912);
  unsigned short* xokT_lo = (unsigned short*)(ws + 14680064);
  float* inv      = (float*)(ws + 16777216);   // 128 KB
  float* U4       = (float*)(ws + 16908288);   // 1 MB (4 slabs of partials)
  float* T        = (float*)(ws + 17956864);   // 256 KB
  double* rowsumH = (double*)(ws + 18219008);  // 16 KB

  rs_kernel <<<dim3(32, NB), 256, 0, stream>>>(x_h, rowsumH);
  prep_qk   <<<dim3(32, NB, 2), 256, 0, stream>>>(x_h, x_o, w_qk, rowsumH,
                                                  xhq_f32, xokT_f32,
                                                  xhq_hi, xokT_hi, xhq_lo, xokT_lo, inv);
  u_kernel  <<<dim3(16, 4, NB), 256, 0, stream>>>(x_o, xokT_f32, inv, U4);
  t_kernel  <<<dim3(8, NB), 256, 0, stream>>>(U4, w_v, b_v, xokT_f32, inv, T);
  xr_kernel <<<dim3(16, NB), 512, 0, stream>>>(xhq_f32, T, out0);
  attn_kernel<<<dim3(32, 32, NB), 256, 0, stream>>>(xhq_hi, xhq_lo, xokT_hi, xokT_lo,
                                                    inv, out1);
}

// Round 6
// 385.572 us; speedup vs baseline: 1.1600x; 1.0040x over previous
//
#include <hip/hip_runtime.h>

constexpr int NTOK = 2048;
constexpr int CH   = 128;
constexpr int C4   = 32;
constexpr int NB   = 16;

typedef __attribute__((ext_vector_type(8))) __bf16 bf16x8;
typedef __attribute__((ext_vector_type(4))) float  f32x4;

__device__ __forceinline__ unsigned short f2bf(float f) {
  union { float f; unsigned u; } v; v.f = f;
  unsigned r = v.u + 0x7fffu + ((v.u >> 16) & 1u);
  return (unsigned short)(r >> 16);
}
__device__ __forceinline__ float bf2f(unsigned short h) {
  union { unsigned u; float f; } v; v.u = ((unsigned)h) << 16;
  return v.f;
}

// rowsumH[b][c] = sum_n x_h[b][c][n]  (fp64) — one wave per channel, no LDS/sync
__global__ __launch_bounds__(256) void rs_kernel(const float* __restrict__ x_h,
                                                 double* __restrict__ rowsumH) {
  const int lane = threadIdx.x & 63;
  const int c = blockIdx.x * 4 + (threadIdx.x >> 6);
  const int b = blockIdx.y;
  const float* rp = x_h + (size_t)(b * CH + c) * NTOK;
  double s = 0.0;
#pragma unroll
  for (int i = 0; i < 8; ++i) {
    float4 v = *(const float4*)(rp + (lane + 64 * i) * 4);
    s += (double)v.x + (double)v.y + (double)v.z + (double)v.w;
  }
  for (int off = 1; off <= 32; off <<= 1) s += __shfl_xor(s, off);
  if (lane == 0) rowsumH[b * CH + c] = s;
}

// q/k projection (fp32 + bf16 hi/lo, [B][N][32] k-contiguous layout).
// which==1 blocks additionally compute P (fp64, per-block redundant),
// inv[m] = 1/(1e-9 + P . x_o[:,m]) for their 64-token slab from LDS-resident Xt,
// and the block's S2 partial: S2[b][d] += sum_{m in slab} xo_k[d][m]*inv[m].
__global__ __launch_bounds__(256) void prep_qk(const float* __restrict__ x_h,
                                               const float* __restrict__ x_o,
                                               const float* __restrict__ w_qk,
                                               const double* __restrict__ rowsumH,
                                               float* __restrict__ xhq_f32,
                                               float* __restrict__ xokT_f32,
                                               unsigned short* __restrict__ xhq_hi,
                                               unsigned short* __restrict__ xokT_hi,
                                               unsigned short* __restrict__ xhq_lo,
                                               unsigned short* __restrict__ xokT_lo,
                                               float* __restrict__ inv,
                                               float* __restrict__ S2g) {
  const int t = threadIdx.x;
  const int n0 = blockIdx.x * 64;
  const int b = blockIdx.y;
  const int which = blockIdx.z;
  const float* src = which ? x_o : x_h;
  float* dstf = which ? xokT_f32 : xhq_f32;
  unsigned short* dsth = which ? xokT_hi : xhq_hi;
  unsigned short* dstl = which ? xokT_lo : xhq_lo;

  __shared__ float Xt[CH][64];
  __shared__ float Wl[C4][132];
  __shared__ double Sl[C4];
  __shared__ double Pl[CH];
  __shared__ float invl[64];
  __shared__ float S2blk[C4];

  for (int i = 0; i < 8; ++i) {
    int flat = t + 256 * i;            // float4 units, 2048 total
    int c = flat >> 4, f4 = flat & 15;
    float4 v = *(const float4*)(src + (size_t)(b * CH + c) * NTOK + n0 + f4 * 4);
    *(float4*)&Xt[c][f4 * 4] = v;
  }
  for (int i = 0; i < 4; ++i) {
    int flat = t + 256 * i;            // float4 units, 1024 total
    int d = flat >> 5, f4 = flat & 31;
    float4 v = *(const float4*)(w_qk + d * CH + f4 * 4);
    *(float4*)&Wl[d][f4 * 4] = v;
  }
  __syncthreads();

  const int nb = (t & 15) * 4;
  const int d0 = (t >> 4) * 2;
  float acc[4][2] = {};
#pragma unroll 4
  for (int c = 0; c < CH; ++c) {
    float4 x4 = *(const float4*)&Xt[c][nb];
    float w0 = Wl[d0][c], w1 = Wl[d0 + 1][c];
    acc[0][0] += x4.x * w0; acc[0][1] += x4.x * w1;
    acc[1][0] += x4.y * w0; acc[1][1] += x4.y * w1;
    acc[2][0] += x4.z * w0; acc[2][1] += x4.z * w1;
    acc[3][0] += x4.w * w0; acc[3][1] += x4.w * w1;
  }

  const size_t robase = (size_t)(b * NTOK + n0 + nb);
#pragma unroll
  for (int i = 0; i < 4; ++i) {
    size_t base = (robase + i) * C4 + d0;
    *(float2*)(dstf + base) = make_float2(acc[i][0], acc[i][1]);
    unsigned short h0 = f2bf(acc[i][0]), h1 = f2bf(acc[i][1]);
    *(unsigned*)(dsth + base) = (unsigned)h0 | ((unsigned)h1 << 16);
    unsigned short l0 = f2bf(acc[i][0] - bf2f(h0));
    unsigned short l1 = f2bf(acc[i][1] - bf2f(h1));
    *(unsigned*)(dstl + base) = (unsigned)l0 | ((unsigned)l1 << 16);
  }

  if (which) {
    // Sl[d] = sum_c w_qk[d][c] * rowsumH[b][c]   (fp64)
    if (t < C4) {
      double s = 0.0;
      for (int c = 0; c < CH; ++c) s += (double)Wl[t][c] * rowsumH[b * CH + c];
      Sl[t] = s;
    }
    if (t < C4) S2blk[t] = 0.f;
    __syncthreads();
    // Pl[c] = sum_d Sl[d] * w_qk[d][c]           (fp64)
    if (t < CH) {
      double p = 0.0;
      for (int d = 0; d < C4; ++d) p += Sl[d] * (double)Wl[d][t];
      Pl[t] = p;
    }
    __syncthreads();
    // inv[m] = 1/(1e-9 + Pl . x_o[:,m]) for the 64 tokens resident in Xt
    if (t < 64) {
      double s = 0.0;
      for (int c = 0; c < CH; ++c) s += Pl[c] * (double)Xt[c][t];
      float ivf = (float)(1.0 / (1e-9 + s));
      inv[b * NTOK + n0 + t] = ivf;
      invl[t] = ivf;
    }
    __syncthreads();
    // S2 partial: this thread holds xo_k[d0..d0+1][n0+nb..+4] in acc
    float s0 = 0.f, s1 = 0.f;
#pragma unroll
    for (int i = 0; i < 4; ++i) {
      float iv = invl[nb + i];
      s0 += acc[i][0] * iv;
      s1 += acc[i][1] * iv;
    }
    atomicAdd(&S2blk[d0], s0);
    atomicAdd(&S2blk[d0 + 1], s1);
    __syncthreads();
    if (t < C4) atomicAdd(&S2g[b * C4 + t], S2blk[t]);
  }
}

// U4[b][slab][d][c'] = sum_{m in slab} xo_k[d][m]*inv[m]*x_o[b][c'][m]
// Thread (g,d) owns m-strip g (32 m per 256-chunk) and ALL 8 c columns:
// 8x fewer K loads than one-c-per-thread; partials reduced through LDS.
__global__ __launch_bounds__(256) void u_kernel(const float* __restrict__ x_o,
                                                const float* __restrict__ xokT_f32,
                                                const float* __restrict__ inv,
                                                float* __restrict__ U4) {
  const int t = threadIdx.x;
  const int c0 = blockIdx.x * 8;
  const int slab = blockIdx.y;
  const int mbase0 = slab * 512;
  const int b = blockIdx.z;
  const int d = t & 31, g = t >> 5;
  __shared__ float Xs[8][256];
  __shared__ float Ured[8][8][32];   // [g][c][d]
  float acc[8] = {};
  for (int cc = 0; cc < 2; ++cc) {
    const int mb = mbase0 + cc * 256;
    __syncthreads();
    for (int i = 0; i < 2; ++i) {
      int flat = t + 256 * i;          // float4 units, 512 total
      int row = flat >> 6, f4 = flat & 63;
      float4 xv = *(const float4*)(x_o + (size_t)(b * CH + c0 + row) * NTOK + mb + f4 * 4);
      float4 iv = *(const float4*)(inv + b * NTOK + mb + f4 * 4);
      xv.x *= iv.x; xv.y *= iv.y; xv.z *= iv.z; xv.w *= iv.w;
      *(float4*)&Xs[row][f4 * 4] = xv;
    }
    __syncthreads();
    const float* ap = xokT_f32 + (size_t)(b * NTOK + mb + g * 32) * C4 + d;
#pragma unroll
    for (int mm = 0; mm < 32; mm += 4) {
      float k0 = ap[(mm + 0) * C4];
      float k1 = ap[(mm + 1) * C4];
      float k2 = ap[(mm + 2) * C4];
      float k3 = ap[(mm + 3) * C4];
#pragma unroll
      for (int c = 0; c < 8; ++c) {
        f32x4 xv = *(const f32x4*)&Xs[c][g * 32 + mm];
        acc[c] += k0 * xv[0] + k1 * xv[1] + k2 * xv[2] + k3 * xv[3];
      }
    }
  }
#pragma unroll
  for (int c = 0; c < 8; ++c) Ured[g][c][d] = acc[c];
  __syncthreads();
  const int d2 = t & 31, c2 = t >> 5;
  float s = 0.f;
#pragma unroll
  for (int g2 = 0; g2 < 8; ++g2) s += Ured[g2][c2][d2];
  U4[(size_t)((b * 4 + slab) * C4 + d2) * CH + c0 + c2] = s;
}

// Fused t+xr: block (cgrp, nslab, b) computes T[b][:, cgrp*16..+16] in LDS
// (redundant per nslab), then out0[b][cgrp*16..+16][nslab*512..+512].
// T never touches global memory.
__global__ __launch_bounds__(256) void txr_kernel(const float* __restrict__ U4,
                                                  const float* __restrict__ w_v,
                                                  const float* __restrict__ b_v,
                                                  const float* __restrict__ S2g,
                                                  const float* __restrict__ xhq_f32,
                                                  float* __restrict__ out0) {
  const int t = threadIdx.x;
  const int cgrp  = blockIdx.x & 7;
  const int nslab = blockIdx.x >> 3;      // 0..3
  const int b = blockIdx.y;
  const int d = t & 31;
  const int g = t >> 5;                   // 0..7
  __shared__ float Wl[16][CH];            // w_v rows cgrp*16 .. +16
  __shared__ float Tl[16][36];            // T[c][d], padded

  for (int i = 0; i < 2; ++i) {
    int flat = t + 256 * i;               // float4 units, 512 total (16*128/4)
    *(float4*)&Wl[0][flat * 4] = *(const float4*)(w_v + (size_t)cgrp * 16 * CH + flat * 4);
  }
  __syncthreads();

  // phase A: T for c pair (2g, 2g+1), row d
  const float s2 = S2g[b * C4 + d];
  const int c0 = g * 2;
  float acc0 = 0.f, acc1 = 0.f;
  const float* up = U4 + (size_t)(b * 4 * C4 + d) * CH;  // slab stride = C4*CH floats
  for (int cp = 0; cp < CH; ++cp) {
    float u = up[cp] + up[C4 * CH + cp] + up[2 * C4 * CH + cp] + up[3 * C4 * CH + cp];
    acc0 += u * Wl[c0][cp];
    acc1 += u * Wl[c0 + 1][cp];
  }
  const int cglob = cgrp * 16 + c0;
  Tl[c0][d]     = acc0 + s2 * b_v[cglob];
  Tl[c0 + 1][d] = acc1 + s2 * b_v[cglob + 1];
  __syncthreads();

  // phase B: out0[b][cgrp*16+c][n] for n in this 512-slab
  const int nbase = nslab * 512;
#pragma unroll
  for (int nn = 0; nn < 2; ++nn) {
    const int n = nbase + nn * 256 + t;
    float xq[C4];
    const float* qp = xhq_f32 + (size_t)(b * NTOK + n) * C4;
#pragma unroll
    for (int i = 0; i < 8; ++i) {
      float4 v = *(const float4*)(qp + i * 4);
      xq[i * 4] = v.x; xq[i * 4 + 1] = v.y; xq[i * 4 + 2] = v.z; xq[i * 4 + 3] = v.w;
    }
    float* op = out0 + (size_t)(b * CH + cgrp * 16) * NTOK + n;
#pragma unroll
    for (int c = 0; c < 16; ++c) {
      float acc = 0.f;
#pragma unroll
      for (int dd = 0; dd < C4; dd += 4) {
        f32x4 tv = *(const f32x4*)&Tl[c][dd];
        acc += xq[dd] * tv[0] + xq[dd + 1] * tv[1] + xq[dd + 2] * tv[2] + xq[dd + 3] * tv[3];
      }
      __builtin_nontemporal_store(acc, op + (size_t)c * NTOK);
    }
  }
}

// attention[b][n][m] = (xh_q[n,:] . xo_k[:,m]) * inv[m], bf16 hi/lo split MFMA.
// Output tile staged in LDS, then stored as full-line 16B nt stores.
__global__ __launch_bounds__(256) void attn_kernel(const unsigned short* __restrict__ xhq_hi,
                                                   const unsigned short* __restrict__ xhq_lo,
                                                   const unsigned short* __restrict__ xokT_hi,
                                                   const unsigned short* __restrict__ xokT_lo,
                                                   const float* __restrict__ inv,
                                                   float* __restrict__ out1) {
  const int t = threadIdx.x;
  const int wave = t >> 6, lane = t & 63;
  const int quad = lane >> 4, l16 = lane & 15;
  const int m0 = blockIdx.x * 64;
  const int n0 = blockIdx.y * 64;
  const int b = blockIdx.z;

  __shared__ float tile[64][68];         // pad 68: writes 2-way (free), reads at b128 floor

  const int n = n0 + wave * 16 + l16;
  const size_t abase = (size_t)(b * NTOK + n) * C4 + quad * 8;
  bf16x8 ah = *(const bf16x8*)(const void*)(xhq_hi + abase);
  bf16x8 al = *(const bf16x8*)(const void*)(xhq_lo + abase);

  bf16x8 bh[4], bl[4];
  float invv[4];
#pragma unroll
  for (int tt = 0; tt < 4; ++tt) {
    int m = m0 + tt * 16 + l16;
    size_t bbase = (size_t)(b * NTOK + m) * C4 + quad * 8;
    bh[tt] = *(const bf16x8*)(const void*)(xokT_hi + bbase);
    bl[tt] = *(const bf16x8*)(const void*)(xokT_lo + bbase);
    invv[tt] = inv[b * NTOK + m];
  }

  const int trow = wave * 16 + quad * 4;
#pragma unroll
  for (int tt = 0; tt < 4; ++tt) {
    f32x4 z = {0.f, 0.f, 0.f, 0.f};
    f32x4 acc = __builtin_amdgcn_mfma_f32_16x16x32_bf16(al, bh[tt], z, 0, 0, 0);
    acc = __builtin_amdgcn_mfma_f32_16x16x32_bf16(ah, bl[tt], acc, 0, 0, 0);
    acc = __builtin_amdgcn_mfma_f32_16x16x32_bf16(ah, bh[tt], acc, 0, 0, 0);
#pragma unroll
    for (int r = 0; r < 4; ++r)
      tile[trow + r][tt * 16 + l16] = acc[r] * invv[tt];
  }
  __syncthreads();

  // read back row-major: wave w covers rows 4w+g (+16s), 16 lanes x 16B = full row
  const int g = lane >> 4;
#pragma unroll
  for (int s = 0; s < 4; ++s) {
    const int row = wave * 4 + g + s * 16;
    f32x4 v = *(const f32x4*)&tile[row][l16 * 4];
    float* dst = out1 + ((size_t)(b * NTOK) + n0 + row) * NTOK + m0 + l16 * 4;
    __builtin_nontemporal_store(v, (f32x4*)dst);
  }
}

extern "C" void kernel_launch(void* const* d_in, const int* in_sizes, int n_in,
                              void* d_out, int out_size, void* d_ws, size_t ws_size,
                              hipStream_t stream) {
  (void)in_sizes; (void)n_in; (void)out_size; (void)ws_size;
  const float* x_h  = (const float*)d_in[0];
  const float* x_o  = (const float*)d_in[1];
  const float* w_qk = (const float*)d_in[2];
  const float* w_v  = (const float*)d_in[3];
  const float* b_v  = (const float*)d_in[4];
  float* out0 = (float*)d_out;
  float* out1 = out0 + (size_t)NB * CH * NTOK;   // 4,194,304 floats

  char* ws = (char*)d_ws;
  float* xhq_f32        = (float*)(ws + 0);
  float* xokT_f32       = (float*)(ws + 4194304);
  unsigned short* xhq_hi  = (unsigned short*)(ws + 8388608);
  unsigned short* xokT_hi = (unsigned short*)(ws + 10485760);
  unsigned short* xhq_lo  = (unsigned short*)(ws + 12582912);
  unsigned short* xokT_lo = (unsigned short*)(ws + 14680064);
  float* inv      = (float*)(ws + 16777216);   // 128 KB
  float* U4       = (float*)(ws + 16908288);   // 1 MB (4 slabs of partials)
  float* S2g      = (float*)(ws + 17956864);   // 2 KB
  double* rowsumH = (double*)(ws + 17959936);  // 16 KB

  hipMemsetAsync(S2g, 0, NB * C4 * sizeof(float), stream);
  rs_kernel <<<dim3(32, NB), 256, 0, stream>>>(x_h, rowsumH);
  prep_qk   <<<dim3(32, NB, 2), 256, 0, stream>>>(x_h, x_o, w_qk, rowsumH,
                                                  xhq_f32, xokT_f32,
                                                  xhq_hi, xokT_hi, xhq_lo, xokT_lo,
                                                  inv, S2g);
  u_kernel  <<<dim3(16, 4, NB), 256, 0, stream>>>(x_o, xokT_f32, inv, U4);
  txr_kernel<<<dim3(32, NB), 256, 0, stream>>>(U4, w_v, b_v, S2g, xhq_f32, out0);
  attn_kernel<<<dim3(32, 32, NB), 256, 0, stream>>>(xhq_hi, xhq_lo, xokT_hi, xokT_lo,
                                                    inv, out1);
}